// Round 8
// baseline (72.933 us; speedup 1.0000x reference)
//
#include <hip/hip_runtime.h>
#include <hip/hip_bf16.h>
#include <stdint.h>

#define B_ 4
#define N_ 2000
#define T_ 12
#define D_ 64
#define K_ 3
#define DEG_ 8
#define E_ (N_*DEG_)              // 16000
#define ROWS_ (B_*N_*T_)          // 96000
#define NT_ (N_*T_)               // 24000
#define EPN_ (B_*T_*D_)           // 3072 elements per node row
#define V4PB_ (T_*D_/4)           // 192 vec4 per (node,b)
#define ROWBYTES_ (EPN_*4)        // 12288 bytes per node row
#define LOG2E_ 1.4426950408889634f

typedef __attribute__((ext_vector_type(8))) short short8v;   // 8 bf16 = 4 VGPR
typedef __attribute__((ext_vector_type(4))) float f32x4;     // MFMA acc

__device__ __forceinline__ uint32_t f32_to_bf16_bits(float x) {
    uint32_t u = __float_as_uint(x);
    return (u + 0x7FFFu + ((u >> 16) & 1u)) >> 16;   // RNE
}
__device__ __forceinline__ uint32_t pack2(float p, float f) {
    return (f32_to_bf16_bits(p) << 16) | f32_to_bf16_bits(f);
}

// ---------- Kernel 0 (prep): WB[c][k] = bf16( c<64 ? Wm[k][c] : log2e*(Wm@W1)[k][c-64] )
//            bpp[d] = log2e * (b_mlp @ W1)[d]        (W1 = W_attn[:64])
// W2/b_attn cancel inside the per-dst softmax; the max-shift also cancels, so
// the logit half is pre-exponentiated downstream. WB is the MFMA B-operand
// (transposed, k-contiguous), in the head of d_out (gcn fully overwrites out).
__global__ void prep_kernel(const float* __restrict__ Wm,
                            const float* __restrict__ Wa,
                            const float* __restrict__ bm,
                            uint16_t* __restrict__ WB,
                            float* __restrict__ bpp) {
    const int tk = threadIdx.x;          // k (or d for bias block)
    const int c  = blockIdx.x;           // 0..128
    if (c < 64) {
        WB[c*64 + tk] = (uint16_t)f32_to_bf16_bits(Wm[tk*64 + c]);
    } else if (c < 128) {
        const int cp = c - 64;
        float s = 0.f;
        #pragma unroll
        for (int e = 0; e < 64; ++e) s += Wm[tk*64 + e] * Wa[e*64 + cp];
        WB[c*64 + tk] = (uint16_t)f32_to_bf16_bits(s * LOG2E_);
    } else {
        float s = 0.f;
        #pragma unroll
        for (int e = 0; e < 64; ++e) s += bm[e] * Wa[e*64 + tk];
        bpp[tk] = s * LOG2E_;
    }
}

// ---------- Kernel 1: MFMA GEMM [96000x64]@[64x128] -> pack (exp2(logit), feat) ----------
// Slim-wave re-tile: block = 16 rows, 4 waves; wave w owns col-tile pair
// {w, w+4} = (feats cols w*16..+15, matching logit cols). Per wave: 4 B-frag
// loads, 4 A-loads (all 4 waves share the same 16 X-rows -> L1 reuse), 4 MFMA,
// acc[2] -> ~64 VGPR, 8 waves/SIMD, 24000 waves total for latency hiding.
// No LDS, no barriers.
__launch_bounds__(256)
__global__ void mlp_mfma(const float* __restrict__ X,
                         const uint16_t* __restrict__ WB,
                         const float* __restrict__ bm,
                         const float* __restrict__ bpp,
                         uint32_t* __restrict__ packed) {
    const int t    = threadIdx.x;
    const int wave = t >> 6, lane = t & 63;
    const int r    = lane & 15, q = lane >> 4;

    const int cf = wave*16 + r;          // feats col (0..63)
    const int cg = cf + 64;              // paired logit col

    // B fragments: lane holds W[k = s*32+q*8 .. +7][col] (k-contiguous in WB)
    short8v bf_f[2], bf_g[2];
    #pragma unroll
    for (int s = 0; s < 2; ++s) {
        bf_f[s] = *(const short8v*)(WB + cf*64 + s*32 + q*8);
        bf_g[s] = *(const short8v*)(WB + cg*64 + s*32 + q*8);
    }

    const int row0 = blockIdx.x * 16;
    f32x4 accf = (f32x4){0.f,0.f,0.f,0.f};
    f32x4 accg = (f32x4){0.f,0.f,0.f,0.f};

    #pragma unroll
    for (int s = 0; s < 2; ++s) {
        const float* xp = X + (size_t)(row0 + r)*64 + s*32 + q*8;
        const float4 x0 = *(const float4*)xp;
        const float4 x1 = *(const float4*)(xp + 4);
        short8v af;
        af[0] = (short)f32_to_bf16_bits(x0.x);
        af[1] = (short)f32_to_bf16_bits(x0.y);
        af[2] = (short)f32_to_bf16_bits(x0.z);
        af[3] = (short)f32_to_bf16_bits(x0.w);
        af[4] = (short)f32_to_bf16_bits(x1.x);
        af[5] = (short)f32_to_bf16_bits(x1.y);
        af[6] = (short)f32_to_bf16_bits(x1.z);
        af[7] = (short)f32_to_bf16_bits(x1.w);
        accf = __builtin_amdgcn_mfma_f32_16x16x32_bf16(af, bf_f[s], accf, 0, 0, 0);
        accg = __builtin_amdgcn_mfma_f32_16x16x32_bf16(af, bf_g[s], accg, 0, 0, 0);
    }

    // Epilogue: C/D layout col=lane&15, row=(lane>>4)*4+reg (validated rounds 7).
    const float bmv = bm[cf];
    const float bpv = bpp[cf];
    #pragma unroll
    for (int reg = 0; reg < 4; ++reg) {
        const float f = accf[reg] + bmv;
        const float g = accg[reg] + bpv;
        const uint32_t u = pack2(__builtin_amdgcn_exp2f(g), f);
        const int gR = row0 + q*4 + reg;           // global row -> (b,n,tt)
        const int b  = gR / NT_;
        const int rm = gR - b*NT_;
        const int n  = rm / T_;
        const int tt = rm - n*T_;
        packed[(size_t)n*EPN_ + b*(T_*D_) + tt*D_ + cf] = u;
    }
}

// ---------- Kernel 2: per-node 8-edge softmax aggregation, K graphs ----------
// Grid (N, 12), 64-thread (1-wave) blocks. Phase-major sub-striping: all blocks
// of phase ss touch only a 2.05 MB byte-stripe of packed (1 KB per row), which
// fits every XCD's 4 MB L2 -> the 24x per-row gather reuse becomes L2 hits
// instead of L3 round trips. No LDS/barrier; edges+weight uniform scalar loads;
// p = exp(logit) precomputed in mlp: softmax = (sum p*f)/(sum p).
__launch_bounds__(64, 4)
__global__ void gcn_kernel(const uint32_t* __restrict__ packed,
                           const float* __restrict__ input,
                           const int* __restrict__ edges,
                           const float* __restrict__ weight,
                           float* __restrict__ out) {
    const int n  = blockIdx.x;
    const int ss = blockIdx.y;            // sub-stripe phase [0,12)
    const int t  = threadIdx.x;           // 64 lanes

    const int vv = ss*64 + t;             // uint4 index within node row [0,768)
    const int b  = vv / V4PB_;
    const int r4 = vv - b*V4PB_;
    const size_t off4 = (size_t)b*(NT_*D_/4) + (size_t)n*V4PB_ + r4;
    const float4 inv = ((const float4*)input)[off4];   // residual, issued early

    float acc[4] = {0.f, 0.f, 0.f, 0.f};

    #pragma unroll
    for (int k = 0; k < K_; ++k) {
        const int4 e0 = *(const int4*)(edges + (size_t)k*(2*E_) + n*DEG_);
        const int4 e1 = *(const int4*)(edges + (size_t)k*(2*E_) + n*DEG_ + 4);
        const float wk = weight[k];
        const int srcs[8] = {e0.x, e0.y, e0.z, e0.w, e1.x, e1.y, e1.z, e1.w};

        uint4 pu[8];
        #pragma unroll
        for (int j = 0; j < 8; ++j) {
            const char* base = (const char*)packed
                             + (size_t)((uint32_t)srcs[j] * (uint32_t)ROWBYTES_);
            pu[j] = *(const uint4*)(base + (size_t)vv * 16);
        }

        #pragma unroll
        for (int qq = 0; qq < 4; ++qq) {
            float s = 0.f, num = 0.f;
            #pragma unroll
            for (int j = 0; j < 8; ++j) {
                const uint32_t u = (qq == 0) ? pu[j].x : (qq == 1) ? pu[j].y
                                 : (qq == 2) ? pu[j].z : pu[j].w;
                const float p = __uint_as_float(u & 0xFFFF0000u);  // exp(logit), bf16
                const float f = __uint_as_float(u << 16);          // feats, bf16
                s += p;
                num = fmaf(p, f, num);
            }
            acc[qq] += wk * num * __builtin_amdgcn_rcpf(s);
        }
    }

    float4 o;
    o.x = (acc[0] > 0.f ? acc[0] : 0.01f*acc[0]) + inv.x;
    o.y = (acc[1] > 0.f ? acc[1] : 0.01f*acc[1]) + inv.y;
    o.z = (acc[2] > 0.f ? acc[2] : 0.01f*acc[2]) + inv.z;
    o.w = (acc[3] > 0.f ? acc[3] : 0.01f*acc[3]) + inv.w;
    ((float4*)out)[off4] = o;
}

extern "C" void kernel_launch(void* const* d_in, const int* in_sizes, int n_in,
                              void* d_out, int out_size, void* d_ws, size_t ws_size,
                              hipStream_t stream) {
    const float* input  = (const float*)d_in[0];
    const float* Wm     = (const float*)d_in[1];
    const float* bm     = (const float*)d_in[2];
    const float* Wa     = (const float*)d_in[3];
    // d_in[4] = b_attn (cancels inside per-dst softmax), unused
    const float* weight = (const float*)d_in[5];
    const int*   edges  = (const int*)d_in[6];
    float* out = (float*)d_out;
    uint32_t* packed = (uint32_t*)d_ws;   // [N][B][T][D] of (bf16 exp(logit) | bf16 feats)

    // Prep scratch lives in the head of d_out; gcn_kernel fully overwrites out.
    uint16_t* WB  = (uint16_t*)d_out;             // 128 cols x 64 k bf16 = 16 KB
    float*    bpp = (float*)d_out + 4096;         // 64 floats

    hipLaunchKernelGGL(prep_kernel, dim3(129), dim3(64), 0, stream, Wm, Wa, bm, WB, bpp);
    hipLaunchKernelGGL(mlp_mfma, dim3(ROWS_/16), dim3(256), 0, stream,
                       input, WB, bm, bpp, packed);
    hipLaunchKernelGGL(gcn_kernel, dim3(N_, 12), dim3(64), 0, stream,
                       packed, input, edges, weight, out);
}

// Round 9
// 66.171 us; speedup vs baseline: 1.1022x; 1.1022x over previous
//
#include <hip/hip_runtime.h>
#include <hip/hip_bf16.h>
#include <stdint.h>

#define B_ 4
#define N_ 2000
#define T_ 12
#define D_ 64
#define K_ 3
#define DEG_ 8
#define E_ (N_*DEG_)              // 16000
#define ROWS_ (B_*N_*T_)          // 96000
#define NT_ (N_*T_)               // 24000
#define EPN_ (B_*T_*D_)           // 3072 elements per node row
#define V4PB_ (T_*D_/4)           // 192 vec4 per (node,b)
#define ROWBYTES_ (EPN_*4)        // 12288 bytes per node row
#define LOG2E_ 1.4426950408889634f

typedef __attribute__((ext_vector_type(8))) short short8v;   // 8 bf16 = 4 VGPR
typedef __attribute__((ext_vector_type(4))) float f32x4;     // MFMA acc

__device__ __forceinline__ uint32_t f32_to_bf16_bits(float x) {
    uint32_t u = __float_as_uint(x);
    return (u + 0x7FFFu + ((u >> 16) & 1u)) >> 16;   // RNE
}
__device__ __forceinline__ uint32_t pack2(float p, float f) {
    return (f32_to_bf16_bits(p) << 16) | f32_to_bf16_bits(f);
}

// ---------- Kernel 0 (prep): WB[c][k] = bf16( c<64 ? Wm[k][c] : log2e*(Wm@W1)[k][c-64] )
//            bpp[d] = log2e * (b_mlp @ W1)[d]        (W1 = W_attn[:64])
// W2/b_attn cancel inside the per-dst softmax; the max-shift also cancels, so
// the logit half is pre-exponentiated downstream. WB is the MFMA B-operand
// (transposed, k-contiguous), in the head of d_out (gcn fully overwrites out).
__global__ void prep_kernel(const float* __restrict__ Wm,
                            const float* __restrict__ Wa,
                            const float* __restrict__ bm,
                            uint16_t* __restrict__ WB,
                            float* __restrict__ bpp) {
    const int tk = threadIdx.x;          // k (or d for bias block)
    const int c  = blockIdx.x;           // 0..128
    if (c < 64) {
        WB[c*64 + tk] = (uint16_t)f32_to_bf16_bits(Wm[tk*64 + c]);
    } else if (c < 128) {
        const int cp = c - 64;
        float s = 0.f;
        #pragma unroll
        for (int e = 0; e < 64; ++e) s += Wm[tk*64 + e] * Wa[e*64 + cp];
        WB[c*64 + tk] = (uint16_t)f32_to_bf16_bits(s * LOG2E_);
    } else {
        float s = 0.f;
        #pragma unroll
        for (int e = 0; e < 64; ++e) s += bm[e] * Wa[e*64 + tk];
        bpp[tk] = s * LOG2E_;
    }
}

// ---------- Kernel 1: MFMA GEMM [96000x64]@[64x128] -> pack (exp2(logit), feat) ----------
// R7 structure (best measured): 64 rows/block, 4 waves; wave = 16 rows x 128 cols
// = 8 col-tiles x 2 K-steps of mfma_f32_16x16x32_bf16. A cvt'd from global f32,
// B from a 16 KB L1-resident table. No LDS, no barriers.
__launch_bounds__(256)
__global__ void mlp_mfma(const float* __restrict__ X,
                         const uint16_t* __restrict__ WB,
                         const float* __restrict__ bm,
                         const float* __restrict__ bpp,
                         uint32_t* __restrict__ packed) {
    const int t    = threadIdx.x;
    const int wave = t >> 6, lane = t & 63;
    const int r    = lane & 15, q = lane >> 4;

    // B fragments: lane holds W[k=s*32+q*8 .. +7][c=tile*16+r] (k-contiguous in WB)
    short8v bfrag[8][2];
    #pragma unroll
    for (int tile = 0; tile < 8; ++tile) {
        const int c = tile*16 + r;
        #pragma unroll
        for (int s = 0; s < 2; ++s)
            bfrag[tile][s] = *(const short8v*)(WB + c*64 + s*32 + q*8);
    }

    const int row0 = blockIdx.x*64 + wave*16;

    f32x4 acc[8];
    #pragma unroll
    for (int tile = 0; tile < 8; ++tile) acc[tile] = (f32x4){0.f,0.f,0.f,0.f};

    #pragma unroll
    for (int s = 0; s < 2; ++s) {
        const float* xp = X + (size_t)(row0 + r)*64 + s*32 + q*8;
        const float4 x0 = *(const float4*)xp;
        const float4 x1 = *(const float4*)(xp + 4);
        short8v af;
        af[0] = (short)f32_to_bf16_bits(x0.x);
        af[1] = (short)f32_to_bf16_bits(x0.y);
        af[2] = (short)f32_to_bf16_bits(x0.z);
        af[3] = (short)f32_to_bf16_bits(x0.w);
        af[4] = (short)f32_to_bf16_bits(x1.x);
        af[5] = (short)f32_to_bf16_bits(x1.y);
        af[6] = (short)f32_to_bf16_bits(x1.z);
        af[7] = (short)f32_to_bf16_bits(x1.w);
        #pragma unroll
        for (int tile = 0; tile < 8; ++tile)
            acc[tile] = __builtin_amdgcn_mfma_f32_16x16x32_bf16(
                            af, bfrag[tile][s], acc[tile], 0, 0, 0);
    }

    // Epilogue: C/D layout col=lane&15, row=(lane>>4)*4+reg (validated round 7).
    // Tile pair (tile, tile+4) = (feats col cf, logit col cf+64).
    #pragma unroll
    for (int tile = 0; tile < 4; ++tile) {
        const int cf  = tile*16 + r;
        const float bmv = bm[cf];
        const float bpv = bpp[cf];
        #pragma unroll
        for (int reg = 0; reg < 4; ++reg) {
            const float f = acc[tile][reg]   + bmv;
            const float g = acc[tile+4][reg] + bpv;
            const uint32_t u = pack2(__builtin_amdgcn_exp2f(g), f);
            const int gR = row0 + q*4 + reg;           // global row -> (b,n,tt)
            const int b  = gR / NT_;
            const int rm = gR - b*NT_;
            const int n  = rm / T_;
            const int tt = rm - n*T_;
            packed[(size_t)n*EPN_ + b*(T_*D_) + tt*D_ + cf] = u;
        }
    }
}

// ---------- Kernel 2: per-node 8-edge softmax aggregation, K graphs ----------
// Grid (1000, 12), 128-thread blocks = 2 waves = 2 nodes of the SAME phase.
// 2-wave blocks double the occupancy ceiling (16 wg/CU cap -> 32 waves/CU).
// Phase-major sub-striping kept: phase ss touches a 2.05 MB byte-stripe of
// packed -> XCD-L2-resident gathers. All 24 gather loads flat-hoisted into
// pu[24] (~120 VGPR) so the whole batch is in flight before any compute.
__launch_bounds__(128, 4)
__global__ void gcn_kernel(const uint32_t* __restrict__ packed,
                           const float* __restrict__ input,
                           const int* __restrict__ edges,
                           const float* __restrict__ weight,
                           float* __restrict__ out) {
    const int wv = __builtin_amdgcn_readfirstlane(threadIdx.x >> 6);  // wave id 0/1
    const int n  = blockIdx.x*2 + wv;
    const int ss = blockIdx.y;            // sub-stripe phase [0,12)
    const int t  = threadIdx.x & 63;      // lane

    const int vv = ss*64 + t;             // uint4 index within node row [0,768)
    const int b  = vv / V4PB_;
    const int r4 = vv - b*V4PB_;
    const size_t off4 = (size_t)b*(NT_*D_/4) + (size_t)n*V4PB_ + r4;
    const float4 inv = ((const float4*)input)[off4];   // residual, issued early

    // Wave-uniform edge indices (SGPR) for all 3 graphs.
    int srcs[24];
    #pragma unroll
    for (int k = 0; k < K_; ++k) {
        const int4 e0 = *(const int4*)(edges + (size_t)k*(2*E_) + n*DEG_);
        const int4 e1 = *(const int4*)(edges + (size_t)k*(2*E_) + n*DEG_ + 4);
        srcs[k*8+0]=e0.x; srcs[k*8+1]=e0.y; srcs[k*8+2]=e0.z; srcs[k*8+3]=e0.w;
        srcs[k*8+4]=e1.x; srcs[k*8+5]=e1.y; srcs[k*8+6]=e1.z; srcs[k*8+7]=e1.w;
    }

    // Flat-hoisted gather batch: 24 x uint4.
    uint4 pu[24];
    #pragma unroll
    for (int idx = 0; idx < 24; ++idx) {
        const char* base = (const char*)packed
                         + (size_t)((uint32_t)srcs[idx] * (uint32_t)ROWBYTES_);
        pu[idx] = *(const uint4*)(base + (size_t)vv * 16);
    }

    float acc[4] = {0.f, 0.f, 0.f, 0.f};
    #pragma unroll
    for (int k = 0; k < K_; ++k) {
        const float wk = weight[k];
        const uint32_t* pw = (const uint32_t*)&pu[k*8];
        #pragma unroll
        for (int qq = 0; qq < 4; ++qq) {
            float s = 0.f, num = 0.f;
            #pragma unroll
            for (int j = 0; j < 8; ++j) {
                const uint32_t u = pw[j*4 + qq];
                const float p = __uint_as_float(u & 0xFFFF0000u);  // exp(logit), bf16
                const float f = __uint_as_float(u << 16);          // feats, bf16
                s += p;
                num = fmaf(p, f, num);
            }
            acc[qq] += wk * num * __builtin_amdgcn_rcpf(s);
        }
    }

    float4 o;
    o.x = (acc[0] > 0.f ? acc[0] : 0.01f*acc[0]) + inv.x;
    o.y = (acc[1] > 0.f ? acc[1] : 0.01f*acc[1]) + inv.y;
    o.z = (acc[2] > 0.f ? acc[2] : 0.01f*acc[2]) + inv.z;
    o.w = (acc[3] > 0.f ? acc[3] : 0.01f*acc[3]) + inv.w;
    ((float4*)out)[off4] = o;
}

extern "C" void kernel_launch(void* const* d_in, const int* in_sizes, int n_in,
                              void* d_out, int out_size, void* d_ws, size_t ws_size,
                              hipStream_t stream) {
    const float* input  = (const float*)d_in[0];
    const float* Wm     = (const float*)d_in[1];
    const float* bm     = (const float*)d_in[2];
    const float* Wa     = (const float*)d_in[3];
    // d_in[4] = b_attn (cancels inside per-dst softmax), unused
    const float* weight = (const float*)d_in[5];
    const int*   edges  = (const int*)d_in[6];
    float* out = (float*)d_out;
    uint32_t* packed = (uint32_t*)d_ws;   // [N][B][T][D] of (bf16 exp(logit) | bf16 feats)

    // Prep scratch lives in the head of d_out; gcn_kernel fully overwrites out.
    uint16_t* WB  = (uint16_t*)d_out;             // 128 cols x 64 k bf16 = 16 KB
    float*    bpp = (float*)d_out + 4096;         // 64 floats

    hipLaunchKernelGGL(prep_kernel, dim3(129), dim3(64), 0, stream, Wm, Wa, bm, WB, bpp);
    hipLaunchKernelGGL(mlp_mfma, dim3(ROWS_/64), dim3(256), 0, stream,
                       input, WB, bm, bpp, packed);
    hipLaunchKernelGGL(gcn_kernel, dim3(N_/2, 12), dim3(128), 0, stream,
                       packed, input, edges, weight, out);
}

// Round 10
// 54.899 us; speedup vs baseline: 1.3285x; 1.2053x over previous
//
#include <hip/hip_runtime.h>
#include <hip/hip_bf16.h>
#include <stdint.h>

#define B_ 4
#define N_ 2000
#define T_ 12
#define D_ 64
#define K_ 3
#define DEG_ 8
#define E_ (N_*DEG_)              // 16000
#define ROWS_ (B_*N_*T_)          // 96000
#define NT_ (N_*T_)               // 24000
#define EPN_ (B_*T_*D_)           // 3072 elements per node row
#define V4PB_ (T_*D_/4)           // 192 vec4 per (node,b)
#define ROWBYTES_ (EPN_*4)        // 12288 bytes per node row
#define LOG2E_ 1.4426950408889634f

typedef __attribute__((ext_vector_type(8))) short short8v;   // 8 bf16 = 4 VGPR
typedef __attribute__((ext_vector_type(4))) float f32x4;     // MFMA acc

__device__ __forceinline__ uint32_t f32_to_bf16_bits(float x) {
    uint32_t u = __float_as_uint(x);
    return (u + 0x7FFFu + ((u >> 16) & 1u)) >> 16;   // RNE
}
__device__ __forceinline__ uint32_t pack2(float p, float f) {
    return (f32_to_bf16_bits(p) << 16) | f32_to_bf16_bits(f);
}

// ---------- Kernel 0 (prep): WB[c][k] = bf16( c<64 ? Wm[k][c] : log2e*(Wm@W1)[k][c-64] )
//            bpp[d] = log2e * (b_mlp @ W1)[d]        (W1 = W_attn[:64])
// W2/b_attn cancel inside the per-dst softmax; the max-shift also cancels, so
// the logit half is pre-exponentiated downstream. WB is the MFMA B-operand
// (transposed, k-contiguous), in the head of d_out (gcn fully overwrites out).
__global__ void prep_kernel(const float* __restrict__ Wm,
                            const float* __restrict__ Wa,
                            const float* __restrict__ bm,
                            uint16_t* __restrict__ WB,
                            float* __restrict__ bpp) {
    const int tk = threadIdx.x;          // k (or d for bias block)
    const int c  = blockIdx.x;           // 0..128
    if (c < 64) {
        WB[c*64 + tk] = (uint16_t)f32_to_bf16_bits(Wm[tk*64 + c]);
    } else if (c < 128) {
        const int cp = c - 64;
        float s = 0.f;
        #pragma unroll
        for (int e = 0; e < 64; ++e) s += Wm[tk*64 + e] * Wa[e*64 + cp];
        WB[c*64 + tk] = (uint16_t)f32_to_bf16_bits(s * LOG2E_);
    } else {
        float s = 0.f;
        #pragma unroll
        for (int e = 0; e < 64; ++e) s += bm[e] * Wa[e*64 + tk];
        bpp[tk] = s * LOG2E_;
    }
}

// ---------- Kernel 1: MFMA GEMM [96000x64]@[64x128] -> pack (exp2(logit), feat) ----------
// R7 structure (best measured): 64 rows/block, 4 waves; wave = 16 rows x 128 cols
// = 8 col-tiles x 2 K-steps of mfma_f32_16x16x32_bf16. A cvt'd from global f32,
// B from a 16 KB L1-resident table. No LDS, no barriers.
__launch_bounds__(256)
__global__ void mlp_mfma(const float* __restrict__ X,
                         const uint16_t* __restrict__ WB,
                         const float* __restrict__ bm,
                         const float* __restrict__ bpp,
                         uint32_t* __restrict__ packed) {
    const int t    = threadIdx.x;
    const int wave = t >> 6, lane = t & 63;
    const int r    = lane & 15, q = lane >> 4;

    // B fragments: lane holds W[k=s*32+q*8 .. +7][c=tile*16+r] (k-contiguous in WB)
    short8v bfrag[8][2];
    #pragma unroll
    for (int tile = 0; tile < 8; ++tile) {
        const int c = tile*16 + r;
        #pragma unroll
        for (int s = 0; s < 2; ++s)
            bfrag[tile][s] = *(const short8v*)(WB + c*64 + s*32 + q*8);
    }

    const int row0 = blockIdx.x*64 + wave*16;

    f32x4 acc[8];
    #pragma unroll
    for (int tile = 0; tile < 8; ++tile) acc[tile] = (f32x4){0.f,0.f,0.f,0.f};

    #pragma unroll
    for (int s = 0; s < 2; ++s) {
        const float* xp = X + (size_t)(row0 + r)*64 + s*32 + q*8;
        const float4 x0 = *(const float4*)xp;
        const float4 x1 = *(const float4*)(xp + 4);
        short8v af;
        af[0] = (short)f32_to_bf16_bits(x0.x);
        af[1] = (short)f32_to_bf16_bits(x0.y);
        af[2] = (short)f32_to_bf16_bits(x0.z);
        af[3] = (short)f32_to_bf16_bits(x0.w);
        af[4] = (short)f32_to_bf16_bits(x1.x);
        af[5] = (short)f32_to_bf16_bits(x1.y);
        af[6] = (short)f32_to_bf16_bits(x1.z);
        af[7] = (short)f32_to_bf16_bits(x1.w);
        #pragma unroll
        for (int tile = 0; tile < 8; ++tile)
            acc[tile] = __builtin_amdgcn_mfma_f32_16x16x32_bf16(
                            af, bfrag[tile][s], acc[tile], 0, 0, 0);
    }

    // Epilogue: C/D layout col=lane&15, row=(lane>>4)*4+reg (validated round 7).
    // Tile pair (tile, tile+4) = (feats col cf, logit col cf+64).
    #pragma unroll
    for (int tile = 0; tile < 4; ++tile) {
        const int cf  = tile*16 + r;
        const float bmv = bm[cf];
        const float bpv = bpp[cf];
        #pragma unroll
        for (int reg = 0; reg < 4; ++reg) {
            const float f = acc[tile][reg]   + bmv;
            const float g = acc[tile+4][reg] + bpv;
            const uint32_t u = pack2(__builtin_amdgcn_exp2f(g), f);
            const int gR = row0 + q*4 + reg;           // global row -> (b,n,tt)
            const int b  = gR / NT_;
            const int rm = gR - b*NT_;
            const int n  = rm / T_;
            const int tt = rm - n*T_;
            packed[(size_t)n*EPN_ + b*(T_*D_) + tt*D_ + cf] = u;
        }
    }
}

// ---------- Kernel 2: per-node 8-edge softmax aggregation, K graphs ----------
// 1D grid of 12000 blocks (2 waves = 2 nodes each), XCD-phase partitioned:
// assuming round-robin wg->XCD (xcd = wgid%8), XCD x processes virtual work
// vw = x*1500 + (wgid>>3), phase-major. Each XCD thus owns a CONTIGUOUS
// 1.5-phase span: its L2 holds 1-2 byte-stripes (2-4 MB) for the whole kernel
// and each packed byte is HBM-fetched by <=2 XCDs (was 8x refetch = 197 MB,
// the R9-measured HBM wall). Bijective re-index -> no correctness risk if the
// mapping assumption is wrong.
__launch_bounds__(128, 4)
__global__ void gcn_kernel(const uint32_t* __restrict__ packed,
                           const float* __restrict__ input,
                           const int* __restrict__ edges,
                           const float* __restrict__ weight,
                           float* __restrict__ out) {
    const uint32_t wgid = blockIdx.x;          // [0,12000)
    const uint32_t xcd  = wgid & 7;            // assumed XCD id (round-robin)
    const uint32_t slot = wgid >> 3;           // [0,1500) within XCD
    const uint32_t vw   = xcd * 1500u + slot;  // phase-major virtual work item
    const int ss   = (int)(vw / 1000u);        // phase [0,12)
    const int pair = (int)(vw - (uint32_t)ss * 1000u);   // [0,1000)

    const int wv = __builtin_amdgcn_readfirstlane(threadIdx.x >> 6);  // wave 0/1
    const int n  = pair*2 + wv;
    const int t  = threadIdx.x & 63;      // lane

    const int vv = ss*64 + t;             // uint4 index within node row [0,768)
    const int b  = vv / V4PB_;
    const int r4 = vv - b*V4PB_;
    const size_t off4 = (size_t)b*(NT_*D_/4) + (size_t)n*V4PB_ + r4;
    const float4 inv = ((const float4*)input)[off4];   // residual, issued early

    // Wave-uniform edge indices (SGPR) for all 3 graphs.
    int srcs[24];
    #pragma unroll
    for (int k = 0; k < K_; ++k) {
        const int4 e0 = *(const int4*)(edges + (size_t)k*(2*E_) + n*DEG_);
        const int4 e1 = *(const int4*)(edges + (size_t)k*(2*E_) + n*DEG_ + 4);
        srcs[k*8+0]=e0.x; srcs[k*8+1]=e0.y; srcs[k*8+2]=e0.z; srcs[k*8+3]=e0.w;
        srcs[k*8+4]=e1.x; srcs[k*8+5]=e1.y; srcs[k*8+6]=e1.z; srcs[k*8+7]=e1.w;
    }

    uint4 pu[24];
    #pragma unroll
    for (int idx = 0; idx < 24; ++idx) {
        const char* base = (const char*)packed
                         + (size_t)((uint32_t)srcs[idx] * (uint32_t)ROWBYTES_);
        pu[idx] = *(const uint4*)(base + (size_t)vv * 16);
    }

    float acc[4] = {0.f, 0.f, 0.f, 0.f};
    #pragma unroll
    for (int k = 0; k < K_; ++k) {
        const float wk = weight[k];
        const uint32_t* pw = (const uint32_t*)&pu[k*8];
        #pragma unroll
        for (int qq = 0; qq < 4; ++qq) {
            float s = 0.f, num = 0.f;
            #pragma unroll
            for (int j = 0; j < 8; ++j) {
                const uint32_t u = pw[j*4 + qq];
                const float p = __uint_as_float(u & 0xFFFF0000u);  // exp(logit), bf16
                const float f = __uint_as_float(u << 16);          // feats, bf16
                s += p;
                num = fmaf(p, f, num);
            }
            acc[qq] += wk * num * __builtin_amdgcn_rcpf(s);
        }
    }

    float4 o;
    o.x = (acc[0] > 0.f ? acc[0] : 0.01f*acc[0]) + inv.x;
    o.y = (acc[1] > 0.f ? acc[1] : 0.01f*acc[1]) + inv.y;
    o.z = (acc[2] > 0.f ? acc[2] : 0.01f*acc[2]) + inv.z;
    o.w = (acc[3] > 0.f ? acc[3] : 0.01f*acc[3]) + inv.w;
    ((float4*)out)[off4] = o;
}

extern "C" void kernel_launch(void* const* d_in, const int* in_sizes, int n_in,
                              void* d_out, int out_size, void* d_ws, size_t ws_size,
                              hipStream_t stream) {
    const float* input  = (const float*)d_in[0];
    const float* Wm     = (const float*)d_in[1];
    const float* bm     = (const float*)d_in[2];
    const float* Wa     = (const float*)d_in[3];
    // d_in[4] = b_attn (cancels inside per-dst softmax), unused
    const float* weight = (const float*)d_in[5];
    const int*   edges  = (const int*)d_in[6];
    float* out = (float*)d_out;
    uint32_t* packed = (uint32_t*)d_ws;   // [N][B][T][D] of (bf16 exp(logit) | bf16 feats)

    // Prep scratch lives in the head of d_out; gcn_kernel fully overwrites out.
    uint16_t* WB  = (uint16_t*)d_out;             // 128 cols x 64 k bf16 = 16 KB
    float*    bpp = (float*)d_out + 4096;         // 64 floats

    hipLaunchKernelGGL(prep_kernel, dim3(129), dim3(64), 0, stream, Wm, Wa, bm, WB, bpp);
    hipLaunchKernelGGL(mlp_mfma, dim3(ROWS_/64), dim3(256), 0, stream,
                       input, WB, bm, bpp, packed);
    hipLaunchKernelGGL(gcn_kernel, dim3(12000), dim3(128), 0, stream,
                       packed, input, edges, weight, out);
}